// Round 1
// baseline (4205.172 us; speedup 1.0000x reference)
//
#include <hip/hip_runtime.h>
#include <hip/hip_bf16.h>

#define S 4096
#define E 256
#define HH 256
#define G4 1024
#define TT 16
#define NEG_ -10000.0f
#define START_ 14
#define STOP_ 15

// ---------- fast math helpers ----------
__device__ __forceinline__ float fast_exp(float x) {           // e^x
    return __builtin_amdgcn_exp2f(x * 1.4426950408889634f);
}
__device__ __forceinline__ float fast_sigmoid(float x) {
    float e = __builtin_amdgcn_exp2f(-1.4426950408889634f * x);
    return __builtin_amdgcn_rcpf(1.0f + e);
}
__device__ __forceinline__ float fast_tanh(float x) {
    float xx = fminf(fmaxf(x, -40.f), 40.f);
    float e = __builtin_amdgcn_exp2f(2.8853900817779268f * xx); // e^{2x}
    return (e - 1.0f) * __builtin_amdgcn_rcpf(e + 1.0f);
}
__device__ __forceinline__ float fast_log(float x) {           // ln
    return 0.6931471805599453f * __builtin_amdgcn_logf(x);
}

#if __has_builtin(__builtin_amdgcn_sdot4)
__device__ __forceinline__ int dot4(int a, int b, int c) {
    return __builtin_amdgcn_sdot4(a, b, c, false);
}
#else
__device__ __forceinline__ int dot4(int a, int b, int c) {
    int d;
    asm("v_dot4_i32_i8 %0, %1, %2, %3" : "=v"(d) : "v"(a), "v"(b), "v"(c));
    return d;
}
#endif

// ---------- K0: quantize W_hh (per-row int8) and h0 ----------
__global__ __launch_bounds__(64) void quant_kernel(
    const float* __restrict__ Wf, const float* __restrict__ Wb,
    const float* __restrict__ h0,
    int* __restrict__ wq, float* __restrict__ wscale,
    int* __restrict__ hq0, float* __restrict__ sh0)
{
    int blk = blockIdx.x, lane = threadIdx.x;  // 64 threads = 1 wave
    const float* src;
    if (blk < 2048) {
        int d = blk >> 10, r = blk & 1023;
        src = (d == 0 ? Wf : Wb) + (size_t)r * 256;
        float4 v = ((const float4*)src)[lane];
        float m = fmaxf(fmaxf(fabsf(v.x), fabsf(v.y)), fmaxf(fabsf(v.z), fabsf(v.w)));
        #pragma unroll
        for (int off = 1; off < 64; off <<= 1) m = fmaxf(m, __shfl_xor(m, off, 64));
        float inv = 127.0f / m;
        int q0 = __float2int_rn(v.x * inv) & 255;
        int q1 = __float2int_rn(v.y * inv) & 255;
        int q2 = __float2int_rn(v.z * inv) & 255;
        int q3 = __float2int_rn(v.w * inv) & 255;
        wq[((size_t)(blk)) * 64 + lane] = q0 | (q1 << 8) | (q2 << 16) | (q3 << 24);
        if (lane == 0) wscale[blk] = m / 127.0f;
    } else {
        int d = blk - 2048;
        src = h0 + (size_t)d * 256;
        float4 v = ((const float4*)src)[lane];
        float m = fmaxf(fmaxf(fabsf(v.x), fabsf(v.y)), fmaxf(fabsf(v.z), fabsf(v.w)));
        #pragma unroll
        for (int off = 1; off < 64; off <<= 1) m = fmaxf(m, __shfl_xor(m, off, 64));
        float inv = 127.0f / m;
        int q0 = __float2int_rn(v.x * inv) & 255;
        int q1 = __float2int_rn(v.y * inv) & 255;
        int q2 = __float2int_rn(v.z * inv) & 255;
        int q3 = __float2int_rn(v.w * inv) & 255;
        hq0[d * 64 + lane] = q0 | (q1 << 8) | (q2 << 16) | (q3 << 24);
        if (lane == 0) sh0[d] = m / 127.0f;
    }
}

// ---------- K1: xg[d][t][r] = b[r] + sum_e W_ih[r][e] * embed[sent][e] ----------
__global__ __launch_bounds__(256) void xg_kernel(
    const int* __restrict__ sent, const float* __restrict__ embed,
    const float* __restrict__ Wf, const float* __restrict__ bihf, const float* __restrict__ bhhf,
    const float* __restrict__ Wb, const float* __restrict__ bihb, const float* __restrict__ bhhb,
    float* __restrict__ xg)
{
    const int dir = blockIdx.y;
    const int t0 = blockIdx.x * 16;
    const int tid = threadIdx.x;
    const float* W = dir ? Wb : Wf;
    __shared__ float xt[16][256];
    for (int tt = 0; tt < 16; ++tt) {
        int t = t0 + tt;
        int pos = dir ? (S - 1 - t) : t;
        int w = sent[pos];
        xt[tt][tid] = embed[(size_t)w * 256 + tid];
    }
    __syncthreads();
    float acc[4][16];
    #pragma unroll
    for (int rc = 0; rc < 4; ++rc)
        #pragma unroll
        for (int tt = 0; tt < 16; ++tt) acc[rc][tt] = 0.f;
    for (int e = 0; e < 256; ++e) {
        float xv[16];
        #pragma unroll
        for (int tt = 0; tt < 16; ++tt) xv[tt] = xt[tt][e];
        #pragma unroll
        for (int rc = 0; rc < 4; ++rc) {
            float w = W[(size_t)(rc * 256 + tid) * 256 + e];
            #pragma unroll
            for (int tt = 0; tt < 16; ++tt) acc[rc][tt] += w * xv[tt];
        }
    }
    const float* bih = dir ? bihb : bihf;
    const float* bhh = dir ? bhhb : bhhf;
    #pragma unroll
    for (int rc = 0; rc < 4; ++rc) {
        int r = rc * 256 + tid;
        float b = bih[r] + bhh[r];
        for (int tt = 0; tt < 16; ++tt)
            xg[((size_t)dir * S + (t0 + tt)) * 1024 + r] = acc[rc][tt] + b;
    }
}

// ---------- K2: sequential LSTM, one block per direction ----------
// 512 threads; thread t owns gate rows r1=t (i/f) and r2=t+512 (g/o).
// W_hh int8 resident in VGPRs; h broadcast via LDS int8.
__global__ __launch_bounds__(512, 2) void lstm_kernel(
    const float* __restrict__ xg, const int* __restrict__ wq,
    const float* __restrict__ wscale, const int* __restrict__ hq0,
    const float* __restrict__ sh0, const float* __restrict__ c0,
    float* __restrict__ hs)
{
    const int d = blockIdx.x;
    const int t = threadIdx.x;
    const int j = t & 255;
    const int half = t >> 8;
    const int r1 = t, r2 = t + 512;

    __shared__ alignas(16) int hq[64];
    __shared__ float pre[1024];

    int w1[64], w2[64];
    {
        const int* wp = wq + ((size_t)d * 1024 + r1) * 64;
        #pragma unroll
        for (int k = 0; k < 64; ++k) w1[k] = wp[k];
        wp = wq + ((size_t)d * 1024 + r2) * 64;
        #pragma unroll
        for (int k = 0; k < 64; ++k) w2[k] = wp[k];
    }
    const float s1 = wscale[d * 1024 + r1];
    const float s2 = wscale[d * 1024 + r2];
    if (t < 64) hq[t] = hq0[d * 64 + t];
    float c = c0[d * 256 + j];
    float sh = sh0[d];
    const float* xgd = xg + (size_t)d * S * 1024;
    float xa1 = xgd[r1], xa2 = xgd[r2];
    float xb1 = xgd[1024 + r1], xb2 = xgd[1024 + r2];
    float* hsd = hs + (size_t)d * S * 256;
    __syncthreads();

    for (int step = 0; step < S; ++step) {
        // prefetch xg for step+2 (depth-2 latency hiding)
        float xn1 = 0.f, xn2 = 0.f;
        if (step + 2 < S) {
            const float* p = xgd + (size_t)(step + 2) * 1024;
            xn1 = p[r1]; xn2 = p[r2];
        }
        int a1 = 0, a2 = 0;
        #pragma unroll
        for (int kb = 0; kb < 4; ++kb) {
            int hv[16];
            #pragma unroll
            for (int q = 0; q < 4; ++q) {
                int4 h4 = ((const int4*)hq)[kb * 4 + q];   // LDS b128 broadcast
                hv[q * 4 + 0] = h4.x; hv[q * 4 + 1] = h4.y;
                hv[q * 4 + 2] = h4.z; hv[q * 4 + 3] = h4.w;
            }
            #pragma unroll
            for (int q = 0; q < 16; ++q) {
                a1 = dot4(w1[kb * 16 + q], hv[q], a1);
                a2 = dot4(w2[kb * 16 + q], hv[q], a2);
            }
        }
        float p1 = xa1 + s1 * sh * (float)a1;
        float p2 = xa2 + s2 * sh * (float)a2;
        pre[r1] = p1;
        pre[r2] = p2;
        __syncthreads();
        float pi = pre[j], pf = pre[256 + j], pg = pre[512 + j], po = pre[768 + j];
        float ig = fast_sigmoid(pi);
        float fg = fast_sigmoid(pf);
        float gg = fast_tanh(pg);
        float og = fast_sigmoid(po);
        c = fg * c + ig * gg;
        float h = og * fast_tanh(c);
        if (half == 0) {
            hsd[(size_t)step * 256 + j] = h;
        } else {
            int qv = __float2int_rn(h * 127.0f);
            ((signed char*)hq)[j] = (signed char)qv;
        }
        sh = 1.0f / 127.0f;
        xa1 = xb1; xa2 = xb2; xb1 = xn1; xb2 = xn2;
        __syncthreads();
    }
}

// ---------- K3: feats[t][tag] = b_out[tag] + W_out[tag] . [hf[t], hb[t]] ----------
__global__ __launch_bounds__(256) void feats_kernel(
    const float* __restrict__ hs, const float* __restrict__ Wout,
    const float* __restrict__ bout, float* __restrict__ feats)
{
    __shared__ float Wl[16][513];
    int tid = threadIdx.x;
    for (int i = tid; i < 16 * 512; i += 256) Wl[i >> 9][i & 511] = Wout[i];
    __syncthreads();
    int tt = tid >> 4, tag = tid & 15;
    int tcur = blockIdx.x * 16 + tt;
    const float* hf = hs + (size_t)tcur * 256;
    const float* hb = hs + (size_t)S * 256 + (size_t)(S - 1 - tcur) * 256;
    float acc = bout[tag];
    for (int k = 0; k < 256; ++k) acc += Wl[tag][k] * hf[k];
    for (int k = 0; k < 256; ++k) acc += Wl[tag][256 + k] * hb[k];
    feats[(size_t)tcur * 16 + tag] = acc;
}

// ---------- K4a: CRF chunk products in log semiring ----------
// P_c = A_{c*64+63} o ... o A_{c*64},  A_t[i][j] = trans[i][j] + feats[t][i]
__global__ __launch_bounds__(256) void crf_chunk_kernel(
    const float* __restrict__ feats, const float* __restrict__ trans,
    float* __restrict__ P)
{
    int chunk = blockIdx.x;
    int tid = threadIdx.x;
    int i = tid >> 4, jj = tid & 15;
    __shared__ float Mt[2][16][17];   // Mt[buf][j][k] = M[k][j]
    float tr[16];
    #pragma unroll
    for (int k = 0; k < 16; ++k) tr[k] = trans[i * 16 + k];
    int t0 = chunk * 64;
    float emit = feats[(size_t)t0 * 16 + i];
    Mt[0][jj][i] = tr[jj] + emit;     // init M = A_{t0}
    __syncthreads();
    int cur = 0;
    float em_next = feats[(size_t)(t0 + 1) * 16 + i];
    for (int s = 1; s < 64; ++s) {
        float em = em_next;
        if (s + 1 < 64) em_next = feats[(size_t)(t0 + s + 1) * 16 + i];
        float v[16];
        #pragma unroll
        for (int k = 0; k < 16; ++k) v[k] = tr[k] + Mt[cur][jj][k];
        float m = v[0];
        #pragma unroll
        for (int k = 1; k < 16; ++k) m = fmaxf(m, v[k]);
        float ssum = 0.f;
        #pragma unroll
        for (int k = 0; k < 16; ++k) ssum += fast_exp(v[k] - m);
        float nv = em + m + fast_log(ssum);
        Mt[cur ^ 1][jj][i] = nv;
        cur ^= 1;
        __syncthreads();
    }
    P[((size_t)chunk * 16 + i) * 16 + jj] = Mt[cur][jj][i];
}

// ---------- K4b: fold 64 chunk matrices through alpha, finish with STOP row ----------
__global__ __launch_bounds__(256) void crf_fold_kernel(
    const float* __restrict__ P, const float* __restrict__ trans,
    float* __restrict__ out)
{
    int tid = threadIdx.x;
    int i = tid >> 4, jj = tid & 15;
    __shared__ float alpha[16];
    if (tid < 16) alpha[tid] = (tid == START_) ? 0.0f : NEG_;
    __syncthreads();
    for (int cc = 0; cc < 64; ++cc) {
        float pv = P[((size_t)cc * 16 + i) * 16 + jj];
        float v = pv + alpha[jj];
        float m = v;
        #pragma unroll
        for (int off = 1; off < 16; off <<= 1) m = fmaxf(m, __shfl_xor(m, off, 64));
        float e = fast_exp(v - m);
        #pragma unroll
        for (int off = 1; off < 16; off <<= 1) e += __shfl_xor(e, off, 64);
        float nv = m + fast_log(e);
        __syncthreads();
        if (jj == 0) alpha[i] = nv;
        __syncthreads();
    }
    if (tid < 16) {
        float v = alpha[tid] + trans[STOP_ * 16 + tid];
        float m = v;
        #pragma unroll
        for (int off = 1; off < 16; off <<= 1) m = fmaxf(m, __shfl_xor(m, off, 64));
        float e = fast_exp(v - m);
        #pragma unroll
        for (int off = 1; off < 16; off <<= 1) e += __shfl_xor(e, off, 64);
        if (tid == 0) out[0] = m + fast_log(e);
    }
}

extern "C" void kernel_launch(void* const* d_in, const int* in_sizes, int n_in,
                              void* d_out, int out_size, void* d_ws, size_t ws_size,
                              hipStream_t stream) {
    const int*   sent  = (const int*)d_in[0];
    const float* embed = (const float*)d_in[1];
    const float* Wihf  = (const float*)d_in[2];
    const float* Whhf  = (const float*)d_in[3];
    const float* bihf  = (const float*)d_in[4];
    const float* bhhf  = (const float*)d_in[5];
    const float* Wihb  = (const float*)d_in[6];
    const float* Whhb  = (const float*)d_in[7];
    const float* bihb  = (const float*)d_in[8];
    const float* bhhb  = (const float*)d_in[9];
    const float* Wout  = (const float*)d_in[10];
    const float* bout  = (const float*)d_in[11];
    const float* trans = (const float*)d_in[12];
    const float* h0    = (const float*)d_in[13];
    const float* c0    = (const float*)d_in[14];
    float* out = (float*)d_out;

    char* ws = (char*)d_ws;
    constexpr size_t OFF_XG     = 0;                               // 2*S*1024*4 = 32MB
    constexpr size_t OFF_WQ     = OFF_XG + (size_t)2 * S * 1024 * 4;      // 512KB
    constexpr size_t OFF_WSCALE = OFF_WQ + (size_t)2 * 1024 * 64 * 4;     // 8KB
    constexpr size_t OFF_HQ0    = OFF_WSCALE + 2 * 1024 * 4;              // 512B
    constexpr size_t OFF_SH0    = OFF_HQ0 + 2 * 64 * 4;                   // 256B pad
    constexpr size_t OFF_HS     = OFF_SH0 + 256;                          // 8MB
    constexpr size_t OFF_FEATS  = OFF_HS + (size_t)2 * S * 256 * 4;       // 256KB
    constexpr size_t OFF_P      = OFF_FEATS + (size_t)S * 16 * 4;         // 64KB

    float* xg     = (float*)(ws + OFF_XG);
    int*   wq     = (int*)(ws + OFF_WQ);
    float* wscale = (float*)(ws + OFF_WSCALE);
    int*   hq0    = (int*)(ws + OFF_HQ0);
    float* sh0    = (float*)(ws + OFF_SH0);
    float* hs     = (float*)(ws + OFF_HS);
    float* feats  = (float*)(ws + OFF_FEATS);
    float* P      = (float*)(ws + OFF_P);

    quant_kernel<<<dim3(2050), dim3(64), 0, stream>>>(Whhf, Whhb, h0, wq, wscale, hq0, sh0);
    xg_kernel<<<dim3(256, 2), dim3(256), 0, stream>>>(sent, embed, Wihf, bihf, bhhf,
                                                      Wihb, bihb, bhhb, xg);
    lstm_kernel<<<dim3(2), dim3(512), 0, stream>>>(xg, wq, wscale, hq0, sh0, c0, hs);
    feats_kernel<<<dim3(256), dim3(256), 0, stream>>>(hs, Wout, bout, feats);
    crf_chunk_kernel<<<dim3(64), dim3(256), 0, stream>>>(feats, trans, P);
    crf_fold_kernel<<<dim3(1), dim3(256), 0, stream>>>(P, trans, out);
}

// Round 2
// 3834.647 us; speedup vs baseline: 1.0966x; 1.0966x over previous
//
#include <hip/hip_runtime.h>
#include <hip/hip_bf16.h>

#define S 4096
#define E 256
#define HH 256
#define G4 1024
#define TT 16
#define NEG_ -10000.0f
#define START_ 14
#define STOP_ 15

// ---------- fast math helpers ----------
__device__ __forceinline__ float fast_exp(float x) {           // e^x
    return __builtin_amdgcn_exp2f(x * 1.4426950408889634f);
}
__device__ __forceinline__ float fast_sigmoid(float x) {
    float e = __builtin_amdgcn_exp2f(-1.4426950408889634f * x);
    return __builtin_amdgcn_rcpf(1.0f + e);
}
__device__ __forceinline__ float fast_tanh(float x) {
    float xx = fminf(fmaxf(x, -40.f), 40.f);
    float e = __builtin_amdgcn_exp2f(2.8853900817779268f * xx); // e^{2x}
    return (e - 1.0f) * __builtin_amdgcn_rcpf(e + 1.0f);
}
__device__ __forceinline__ float fast_log(float x) {           // ln
    return 0.6931471805599453f * __builtin_amdgcn_logf(x);
}

#if __has_builtin(__builtin_amdgcn_sdot4)
__device__ __forceinline__ int dot4(int a, int b, int c) {
    return __builtin_amdgcn_sdot4(a, b, c, false);
}
#else
__device__ __forceinline__ int dot4(int a, int b, int c) {
    int d;
    asm("v_dot4_i32_i8 %0, %1, %2, %3" : "=v"(d) : "v"(a), "v"(b), "v"(c));
    return d;
}
#endif

// ---------- K0: quantize W_hh (per-row int8) and h0 ----------
__global__ __launch_bounds__(64) void quant_kernel(
    const float* __restrict__ Wf, const float* __restrict__ Wb,
    const float* __restrict__ h0,
    int* __restrict__ wq, float* __restrict__ wscale,
    int* __restrict__ hq0, float* __restrict__ sh0)
{
    int blk = blockIdx.x, lane = threadIdx.x;  // 64 threads = 1 wave
    const float* src;
    if (blk < 2048) {
        int d = blk >> 10, r = blk & 1023;
        src = (d == 0 ? Wf : Wb) + (size_t)r * 256;
        float4 v = ((const float4*)src)[lane];
        float m = fmaxf(fmaxf(fabsf(v.x), fabsf(v.y)), fmaxf(fabsf(v.z), fabsf(v.w)));
        #pragma unroll
        for (int off = 1; off < 64; off <<= 1) m = fmaxf(m, __shfl_xor(m, off, 64));
        float inv = 127.0f / m;
        int q0 = __float2int_rn(v.x * inv) & 255;
        int q1 = __float2int_rn(v.y * inv) & 255;
        int q2 = __float2int_rn(v.z * inv) & 255;
        int q3 = __float2int_rn(v.w * inv) & 255;
        wq[((size_t)(blk)) * 64 + lane] = q0 | (q1 << 8) | (q2 << 16) | (q3 << 24);
        if (lane == 0) wscale[blk] = m / 127.0f;
    } else {
        int d = blk - 2048;
        src = h0 + (size_t)d * 256;
        float4 v = ((const float4*)src)[lane];
        float m = fmaxf(fmaxf(fabsf(v.x), fabsf(v.y)), fmaxf(fabsf(v.z), fabsf(v.w)));
        #pragma unroll
        for (int off = 1; off < 64; off <<= 1) m = fmaxf(m, __shfl_xor(m, off, 64));
        float inv = 127.0f / m;
        int q0 = __float2int_rn(v.x * inv) & 255;
        int q1 = __float2int_rn(v.y * inv) & 255;
        int q2 = __float2int_rn(v.z * inv) & 255;
        int q3 = __float2int_rn(v.w * inv) & 255;
        hq0[d * 64 + lane] = q0 | (q1 << 8) | (q2 << 16) | (q3 << 24);
        if (lane == 0) sh0[d] = m / 127.0f;
    }
}

// ---------- K1: xg[d][t][r] = b[r] + sum_e W_ih[r][e] * embed[sent][e] ----------
__global__ __launch_bounds__(256) void xg_kernel(
    const int* __restrict__ sent, const float* __restrict__ embed,
    const float* __restrict__ Wf, const float* __restrict__ bihf, const float* __restrict__ bhhf,
    const float* __restrict__ Wb, const float* __restrict__ bihb, const float* __restrict__ bhhb,
    float* __restrict__ xg)
{
    const int dir = blockIdx.y;
    const int t0 = blockIdx.x * 16;
    const int tid = threadIdx.x;
    const float* W = dir ? Wb : Wf;
    __shared__ float xt[16][256];
    for (int tt = 0; tt < 16; ++tt) {
        int t = t0 + tt;
        int pos = dir ? (S - 1 - t) : t;
        int w = sent[pos];
        xt[tt][tid] = embed[(size_t)w * 256 + tid];
    }
    __syncthreads();
    float acc[4][16];
    #pragma unroll
    for (int rc = 0; rc < 4; ++rc)
        #pragma unroll
        for (int tt = 0; tt < 16; ++tt) acc[rc][tt] = 0.f;
    for (int e = 0; e < 256; ++e) {
        float xv[16];
        #pragma unroll
        for (int tt = 0; tt < 16; ++tt) xv[tt] = xt[tt][e];
        #pragma unroll
        for (int rc = 0; rc < 4; ++rc) {
            float w = W[(size_t)(rc * 256 + tid) * 256 + e];
            #pragma unroll
            for (int tt = 0; tt < 16; ++tt) acc[rc][tt] += w * xv[tt];
        }
    }
    const float* bih = dir ? bihb : bihf;
    const float* bhh = dir ? bhhb : bhhf;
    #pragma unroll
    for (int rc = 0; rc < 4; ++rc) {
        int r = rc * 256 + tid;
        float b = bih[r] + bhh[r];
        for (int tt = 0; tt < 16; ++tt)
            xg[((size_t)dir * S + (t0 + tt)) * 1024 + r] = acc[rc][tt] + b;
    }
}

// ---------- K2: sequential LSTM, one block per direction ----------
// 512 threads; lane-pair owns one cell m = t>>1:
//   even lane: rows m (i-gate), 256+m (f-gate)
//   odd  lane: rows 512+m (g-gate), 768+m (o-gate)
// Gate combine via 2x __shfl_xor(.,1) (DPP quad-perm) -> no pre[] LDS trip.
// hq double-buffered -> ONE barrier per step; raw s_barrier keeps xg
// prefetch in flight (no vmcnt drain).
__global__ __launch_bounds__(512, 2) void lstm_kernel(
    const float* __restrict__ xg, const int* __restrict__ wq,
    const float* __restrict__ wscale, const int* __restrict__ hq0,
    const float* __restrict__ sh0, const float* __restrict__ c0,
    float* __restrict__ hs)
{
    const int d = blockIdx.x;
    const int t = threadIdx.x;
    const int m = t >> 1;          // cell index 0..255
    const int odd = t & 1;
    const int r1 = odd * 512 + m;  // i (even) / g (odd)
    const int r2 = r1 + 256;       // f (even) / o (odd)

    __shared__ alignas(16) int hqbuf[2][64];

    int w1[64], w2[64];
    {
        const int4* wp = (const int4*)(wq + ((size_t)d * 1024 + r1) * 64);
        #pragma unroll
        for (int k = 0; k < 16; ++k) {
            int4 v = wp[k];
            w1[k * 4 + 0] = v.x; w1[k * 4 + 1] = v.y;
            w1[k * 4 + 2] = v.z; w1[k * 4 + 3] = v.w;
        }
        wp = (const int4*)(wq + ((size_t)d * 1024 + r2) * 64);
        #pragma unroll
        for (int k = 0; k < 16; ++k) {
            int4 v = wp[k];
            w2[k * 4 + 0] = v.x; w2[k * 4 + 1] = v.y;
            w2[k * 4 + 2] = v.z; w2[k * 4 + 3] = v.w;
        }
    }
    const float s1 = wscale[d * 1024 + r1];
    const float s2 = wscale[d * 1024 + r2];
    if (t < 64) hqbuf[0][t] = hq0[d * 64 + t];
    float c = c0[d * 256 + m];        // meaningful on even lanes only
    float sh = sh0[d];
    const float* xgd = xg + (size_t)d * S * 1024;
    float xa1 = xgd[r1], xa2 = xgd[r2];
    float xb1 = xgd[1024 + r1], xb2 = xgd[1024 + r2];
    float* hsd = hs + (size_t)d * S * 256;
    __syncthreads();

    int cur = 0;
    for (int step = 0; step < S; ++step) {
        // prefetch xg for step+2 (stays in flight across raw s_barrier)
        float xn1 = 0.f, xn2 = 0.f;
        if (step + 2 < S) {
            const float* p = xgd + (size_t)(step + 2) * 1024;
            xn1 = p[r1]; xn2 = p[r2];
        }
        const int4* hb = (const int4*)hqbuf[cur];
        int a1 = 0, a2 = 0;
        #pragma unroll
        for (int kb = 0; kb < 4; ++kb) {
            int hv[16];
            #pragma unroll
            for (int q = 0; q < 4; ++q) {
                int4 h4 = hb[kb * 4 + q];   // LDS b128 broadcast (conflict-free)
                hv[q * 4 + 0] = h4.x; hv[q * 4 + 1] = h4.y;
                hv[q * 4 + 2] = h4.z; hv[q * 4 + 3] = h4.w;
            }
            #pragma unroll
            for (int q = 0; q < 16; ++q) {
                a1 = dot4(w1[kb * 16 + q], hv[q], a1);
                a2 = dot4(w2[kb * 16 + q], hv[q], a2);
            }
        }
        float p1 = xa1 + s1 * sh * (float)a1;   // even: pi | odd: pg
        float p2 = xa2 + s2 * sh * (float)a2;   // even: pf | odd: po
        float q1 = __shfl_xor(p1, 1, 64);       // even gets pg
        float q2 = __shfl_xor(p2, 1, 64);       // even gets po
        if (!odd) {
            float ig = fast_sigmoid(p1);
            float fg = fast_sigmoid(p2);
            float gg = fast_tanh(q1);
            float og = fast_sigmoid(q2);
            c = fg * c + ig * gg;
            float h = og * fast_tanh(c);
            hsd[(size_t)step * 256 + m] = h;
            int qv = __float2int_rn(h * 127.0f);
            ((signed char*)hqbuf[cur ^ 1])[m] = (signed char)qv;
        }
        sh = 1.0f / 127.0f;
        xa1 = xb1; xa2 = xb2; xb1 = xn1; xb2 = xn2;
        // hq writes visible to all, but do NOT drain vmcnt (prefetch lives on)
        asm volatile("s_waitcnt lgkmcnt(0)" ::: "memory");
        __builtin_amdgcn_s_barrier();
        __builtin_amdgcn_sched_barrier(0);
        cur ^= 1;
    }
}

// ---------- K3: feats[t][tag] = b_out[tag] + W_out[tag] . [hf[t], hb[t]] ----------
__global__ __launch_bounds__(256) void feats_kernel(
    const float* __restrict__ hs, const float* __restrict__ Wout,
    const float* __restrict__ bout, float* __restrict__ feats)
{
    __shared__ float Wl[16][513];
    int tid = threadIdx.x;
    for (int i = tid; i < 16 * 512; i += 256) Wl[i >> 9][i & 511] = Wout[i];
    __syncthreads();
    int tt = tid >> 4, tag = tid & 15;
    int tcur = blockIdx.x * 16 + tt;
    const float* hf = hs + (size_t)tcur * 256;
    const float* hb = hs + (size_t)S * 256 + (size_t)(S - 1 - tcur) * 256;
    float acc = bout[tag];
    for (int k = 0; k < 256; ++k) acc += Wl[tag][k] * hf[k];
    for (int k = 0; k < 256; ++k) acc += Wl[tag][256 + k] * hb[k];
    feats[(size_t)tcur * 16 + tag] = acc;
}

// ---------- K4a: CRF chunk products in log semiring ----------
__global__ __launch_bounds__(256) void crf_chunk_kernel(
    const float* __restrict__ feats, const float* __restrict__ trans,
    float* __restrict__ P)
{
    int chunk = blockIdx.x;
    int tid = threadIdx.x;
    int i = tid >> 4, jj = tid & 15;
    __shared__ float Mt[2][16][17];   // Mt[buf][j][k] = M[k][j]
    float tr[16];
    #pragma unroll
    for (int k = 0; k < 16; ++k) tr[k] = trans[i * 16 + k];
    int t0 = chunk * 64;
    float emit = feats[(size_t)t0 * 16 + i];
    Mt[0][jj][i] = tr[jj] + emit;     // init M = A_{t0}
    __syncthreads();
    int cur = 0;
    float em_next = feats[(size_t)(t0 + 1) * 16 + i];
    for (int s = 1; s < 64; ++s) {
        float em = em_next;
        if (s + 1 < 64) em_next = feats[(size_t)(t0 + s + 1) * 16 + i];
        float v[16];
        #pragma unroll
        for (int k = 0; k < 16; ++k) v[k] = tr[k] + Mt[cur][jj][k];
        float m = v[0];
        #pragma unroll
        for (int k = 1; k < 16; ++k) m = fmaxf(m, v[k]);
        float ssum = 0.f;
        #pragma unroll
        for (int k = 0; k < 16; ++k) ssum += fast_exp(v[k] - m);
        float nv = em + m + fast_log(ssum);
        Mt[cur ^ 1][jj][i] = nv;
        cur ^= 1;
        __syncthreads();
    }
    P[((size_t)chunk * 16 + i) * 16 + jj] = Mt[cur][jj][i];
}

// ---------- K4b: fold 64 chunk matrices through alpha ----------
__global__ __launch_bounds__(256) void crf_fold_kernel(
    const float* __restrict__ P, const float* __restrict__ trans,
    float* __restrict__ out)
{
    int tid = threadIdx.x;
    int i = tid >> 4, jj = tid & 15;
    __shared__ float alpha[16];
    if (tid < 16) alpha[tid] = (tid == START_) ? 0.0f : NEG_;
    __syncthreads();
    for (int cc = 0; cc < 64; ++cc) {
        float pv = P[((size_t)cc * 16 + i) * 16 + jj];
        float v = pv + alpha[jj];
        float m = v;
        #pragma unroll
        for (int off = 1; off < 16; off <<= 1) m = fmaxf(m, __shfl_xor(m, off, 64));
        float e = fast_exp(v - m);
        #pragma unroll
        for (int off = 1; off < 16; off <<= 1) e += __shfl_xor(e, off, 64);
        float nv = m + fast_log(e);
        __syncthreads();
        if (jj == 0) alpha[i] = nv;
        __syncthreads();
    }
    if (tid < 16) {
        float v = alpha[tid] + trans[STOP_ * 16 + tid];
        float m = v;
        #pragma unroll
        for (int off = 1; off < 16; off <<= 1) m = fmaxf(m, __shfl_xor(m, off, 64));
        float e = fast_exp(v - m);
        #pragma unroll
        for (int off = 1; off < 16; off <<= 1) e += __shfl_xor(e, off, 64);
        if (tid == 0) out[0] = m + fast_log(e);
    }
}

extern "C" void kernel_launch(void* const* d_in, const int* in_sizes, int n_in,
                              void* d_out, int out_size, void* d_ws, size_t ws_size,
                              hipStream_t stream) {
    const int*   sent  = (const int*)d_in[0];
    const float* embed = (const float*)d_in[1];
    const float* Wihf  = (const float*)d_in[2];
    const float* Whhf  = (const float*)d_in[3];
    const float* bihf  = (const float*)d_in[4];
    const float* bhhf  = (const float*)d_in[5];
    const float* Wihb  = (const float*)d_in[6];
    const float* Whhb  = (const float*)d_in[7];
    const float* bihb  = (const float*)d_in[8];
    const float* bhhb  = (const float*)d_in[9];
    const float* Wout  = (const float*)d_in[10];
    const float* bout  = (const float*)d_in[11];
    const float* trans = (const float*)d_in[12];
    const float* h0    = (const float*)d_in[13];
    const float* c0    = (const float*)d_in[14];
    float* out = (float*)d_out;

    char* ws = (char*)d_ws;
    constexpr size_t OFF_XG     = 0;                               // 2*S*1024*4 = 32MB
    constexpr size_t OFF_WQ     = OFF_XG + (size_t)2 * S * 1024 * 4;      // 512KB
    constexpr size_t OFF_WSCALE = OFF_WQ + (size_t)2 * 1024 * 64 * 4;     // 8KB
    constexpr size_t OFF_HQ0    = OFF_WSCALE + 2 * 1024 * 4;              // 512B
    constexpr size_t OFF_SH0    = OFF_HQ0 + 2 * 64 * 4;                   // 256B pad
    constexpr size_t OFF_HS     = OFF_SH0 + 256;                          // 8MB
    constexpr size_t OFF_FEATS  = OFF_HS + (size_t)2 * S * 256 * 4;       // 256KB
    constexpr size_t OFF_P      = OFF_FEATS + (size_t)S * 16 * 4;         // 64KB

    float* xg     = (float*)(ws + OFF_XG);
    int*   wq     = (int*)(ws + OFF_WQ);
    float* wscale = (float*)(ws + OFF_WSCALE);
    int*   hq0    = (int*)(ws + OFF_HQ0);
    float* sh0    = (float*)(ws + OFF_SH0);
    float* hs     = (float*)(ws + OFF_HS);
    float* feats  = (float*)(ws + OFF_FEATS);
    float* P      = (float*)(ws + OFF_P);

    quant_kernel<<<dim3(2050), dim3(64), 0, stream>>>(Whhf, Whhb, h0, wq, wscale, hq0, sh0);
    xg_kernel<<<dim3(256, 2), dim3(256), 0, stream>>>(sent, embed, Wihf, bihf, bhhf,
                                                      Wihb, bihb, bhhb, xg);
    lstm_kernel<<<dim3(2), dim3(512), 0, stream>>>(xg, wq, wscale, hq0, sh0, c0, hs);
    feats_kernel<<<dim3(256), dim3(256), 0, stream>>>(hs, Wout, bout, feats);
    crf_chunk_kernel<<<dim3(64), dim3(256), 0, stream>>>(feats, trans, P);
    crf_fold_kernel<<<dim3(1), dim3(256), 0, stream>>>(P, trans, out);
}